// Round 10
// baseline (6388.314 us; speedup 1.0000x reference)
//
#include <hip/hip_runtime.h>
#include <math.h>

#define TT 200
#define ST 36    // padded stride (mult of 4): rows 16B-aligned
#define PA 33    // stride for scalar-read LDS copies (A, D)
#define FSTR 17  // stride for F (32x16)

__device__ __forceinline__ float rdlane(float v, int l) {
  return __int_as_float(__builtin_amdgcn_readlane(__float_as_int(v), l));
}

#if __has_builtin(__builtin_amdgcn_rsqf)
#define RSQF(x) __builtin_amdgcn_rsqf(x)
#else
#define RSQF(x) (1.0f / sqrtf(x))
#endif

__device__ __forceinline__ float4 ld4(const float* p) { return *(const float4*)p; }
__device__ __forceinline__ void st4(float* p, float4 v) { *(float4*)p = v; }

// dot of a 32-float LDS row with a register-resident row
__device__ __forceinline__ float dot32r(const float* __restrict__ row, const float (&a)[32]) {
  float s0 = 0.f, s1 = 0.f;
  #pragma unroll
  for (int k = 0; k < 32; k += 8) {
    float4 v0 = ld4(row + k);
    float4 v1 = ld4(row + k + 4);
    s0 = fmaf(a[k+0], v0.x, s0); s0 = fmaf(a[k+1], v0.y, s0);
    s0 = fmaf(a[k+2], v0.z, s0); s0 = fmaf(a[k+3], v0.w, s0);
    s1 = fmaf(a[k+4], v1.x, s1); s1 = fmaf(a[k+5], v1.y, s1);
    s1 = fmaf(a[k+6], v1.z, s1); s1 = fmaf(a[k+7], v1.w, s1);
  }
  return s0 + s1;
}

// one LDS row-read, two register rows -> two dots
__device__ __forceinline__ void dot32x2(const float* __restrict__ row,
                                        const float (&a)[32], const float (&b)[32],
                                        float& oa, float& ob) {
  float a0=0.f, a1=0.f, b0=0.f, b1=0.f;
  #pragma unroll
  for (int k = 0; k < 32; k += 8) {
    float4 v0 = ld4(row + k);
    float4 v1 = ld4(row + k + 4);
    a0 = fmaf(a[k+0], v0.x, a0); a1 = fmaf(a[k+1], v0.y, a1);
    a0 = fmaf(a[k+2], v0.z, a0); a1 = fmaf(a[k+3], v0.w, a1);
    b0 = fmaf(b[k+0], v0.x, b0); b1 = fmaf(b[k+1], v0.y, b1);
    b0 = fmaf(b[k+2], v0.z, b0); b1 = fmaf(b[k+3], v0.w, b1);
    a0 = fmaf(a[k+4], v1.x, a0); a1 = fmaf(a[k+5], v1.y, a1);
    a0 = fmaf(a[k+6], v1.z, a0); a1 = fmaf(a[k+7], v1.w, a1);
    b0 = fmaf(b[k+4], v1.x, b0); b1 = fmaf(b[k+5], v1.y, b1);
    b0 = fmaf(b[k+6], v1.z, b0); b1 = fmaf(b[k+7], v1.w, b1);
  }
  oa = a0 + a1; ob = b0 + b1;
}

// one LDS row-read, four register rows -> four dots
__device__ __forceinline__ void dot32x4(const float* __restrict__ row,
    const float (&a)[32], const float (&b)[32], const float (&c)[32], const float (&d)[32],
    float& oa, float& ob, float& oc, float& od) {
  float sa=0.f, sb=0.f, sc=0.f, sd=0.f;
  #pragma unroll
  for (int k = 0; k < 32; k += 4) {
    float4 v = ld4(row + k);
    sa = fmaf(a[k+0], v.x, sa); sb = fmaf(b[k+0], v.x, sb);
    sc = fmaf(c[k+0], v.x, sc); sd = fmaf(d[k+0], v.x, sd);
    sa = fmaf(a[k+1], v.y, sa); sb = fmaf(b[k+1], v.y, sb);
    sc = fmaf(c[k+1], v.y, sc); sd = fmaf(d[k+1], v.y, sd);
    sa = fmaf(a[k+2], v.z, sa); sb = fmaf(b[k+2], v.z, sb);
    sc = fmaf(c[k+2], v.z, sc); sd = fmaf(d[k+2], v.z, sd);
    sa = fmaf(a[k+3], v.w, sa); sb = fmaf(b[k+3], v.w, sb);
    sc = fmaf(c[k+3], v.w, sc); sd = fmaf(d[k+3], v.w, sd);
  }
  oa = sa; ob = sb; oc = sc; od = sd;
}

// dot of two 32-float LDS rows
__device__ __forceinline__ float dot32rr(const float* __restrict__ ra, const float* __restrict__ rb) {
  float s0 = 0.f, s1 = 0.f;
  #pragma unroll
  for (int k = 0; k < 32; k += 8) {
    float4 x0 = ld4(ra + k), x1 = ld4(ra + k + 4);
    float4 y0 = ld4(rb + k), y1 = ld4(rb + k + 4);
    s0 = fmaf(x0.x, y0.x, s0); s0 = fmaf(x0.y, y0.y, s0);
    s0 = fmaf(x0.z, y0.z, s0); s0 = fmaf(x0.w, y0.w, s0);
    s1 = fmaf(x1.x, y1.x, s1); s1 = fmaf(x1.y, y1.y, s1);
    s1 = fmaf(x1.z, y1.z, s1); s1 = fmaf(x1.w, y1.w, s1);
  }
  return s0 + s1;
}

// launch_bounds(512, 1): grid == 256 blocks == #CUs, so a 2nd block/CU is
// impossible regardless of VGPRs — capping the allocator at 128 (the old
// (512,2) bound) only caused scratch spills (R6/R7: FETCH_SIZE 5 GB).
__global__ void __launch_bounds__(512, 1) kf_kernel(
    const float* __restrict__ Yg, const float* __restrict__ Ug,
    const float* __restrict__ Mg, const float* __restrict__ Ag,
    const float* __restrict__ Bg, const float* __restrict__ Cg,
    const float* __restrict__ mu0g, const float* __restrict__ S0g,
    const float* __restrict__ Qg, const float* __restrict__ Rg,
    float* __restrict__ out, int Bsz)
{
  __shared__ __align__(16) float SIG[32*ST];    // Sigma filtered (symmetric)
  __shared__ __align__(16) float T1[32*ST];     // A @ Sigma
  __shared__ __align__(16) float T1P[32*ST];    // D @ Sigma  (D = C@A)
  __shared__ __align__(16) float SIGP[32*ST];   // Sigma_pred
  __shared__ __align__(16) float T2T[33*ST];    // T2T[j][i] = T2[i][j]; row 32 = residual
  __shared__ __align__(16) float SR[32*ST];     // S (row ~= col by symmetry)
  __shared__ __align__(16) float WT[33*ST];     // WT[cc][j] = W[j][cc]; row 32 = z
  __shared__ __align__(16) float QL[1024];      // Q
  __shared__ __align__(16) float CQT[1024];     // CQT[q*32+r] = (C@Q)[r][q]
  __shared__ __align__(16) float EL[1024];      // E = C@Q@C^T + R
  __shared__ float ALDS[32*PA];                 // A rows, scalar-read
  __shared__ float DLDS[32*PA];                 // D rows, scalar-read
  __shared__ float FL[32*FSTR];                 // F = C@B (32x16)
  __shared__ float u_lds[16], y_lds[32], mupred[32], mu_lds[32], mlds[2];

  const int tid = threadIdx.x;
  const int q = tid >> 5;           // 0..15 -> owns output rows q, q+16
  const int r = tid & 31;           // output column
  const int b = blockIdx.x;
  const long btB = (long)b * TT;

  const long o_Sf = (long)Bsz * TT * 32;
  const long o_mp = o_Sf + (long)Bsz * TT * 32 * 32;
  const long o_Sp = o_mp + (long)Bsz * TT * 32;

  // ---- init 0: stage constants. C temporarily lives in SR (scalar copy, stride PA) ----
  for (int e = tid; e < 1024; e += 512) {
    int i = e >> 5, k = e & 31;
    ALDS[i*PA + k] = Ag[e];
    SR[i*PA + k]   = Cg[e];     // CL alias (clobbered by t-loop later)
    QL[e] = Qg[e];
    SIG[i*ST + k] = S0g[e];
  }
  if (tid < 32) mu_lds[tid] = mu0g[tid];
  if (tid < 16) u_lds[tid] = Ug[btB*16 + tid];
  if (tid >= 64 && tid < 96) y_lds[tid-64] = Yg[btB*32 + (tid-64)];
  if (tid == 224) mlds[0] = Mg[btB];

  // persistent register rows: A rows q, q+16
  float aq0[32], aq1[32];
  #pragma unroll
  for (int k = 0; k < 32; k += 4) {
    float4 v;
    v = ld4(Ag + q*32 + k);      aq0[k]=v.x; aq0[k+1]=v.y; aq0[k+2]=v.z; aq0[k+3]=v.w;
    v = ld4(Ag + (q+16)*32 + k); aq1[k]=v.x; aq1[k+1]=v.y; aq1[k+2]=v.z; aq1[k+3]=v.w;
  }
  __syncthreads();

  // ---- init 1: D = C@A, CQT[q*32+r] = (C@Q)[r][q], F = C@B ----
  {
    float d0 = 0.f, d1 = 0.f, x0 = 0.f, x1 = 0.f;
    #pragma unroll 8
    for (int k = 0; k < 32; ++k) {
      float al = ALDS[k*PA + r];
      d0 = fmaf(SR[q*PA + k],      al, d0);
      d1 = fmaf(SR[(q+16)*PA + k], al, d1);
      float cl = SR[r*PA + k];
      x0 = fmaf(cl, QL[k*32 + q],      x0);
      x1 = fmaf(cl, QL[k*32 + q + 16], x1);
    }
    DLDS[q*PA + r] = d0; DLDS[(q+16)*PA + r] = d1;
    CQT[q*32 + r] = x0;  CQT[(q+16)*32 + r] = x1;
    const int fi = tid >> 4, fj = tid & 15;   // 32x16 = 512 outputs
    float f = 0.f;
    #pragma unroll 8
    for (int k = 0; k < 32; ++k) f = fmaf(SR[fi*PA + k], Bg[k*16 + fj], f);
    FL[fi*FSTR + fj] = f;
  }
  __syncthreads();

  // ---- init 2: E = CQ@C^T + R ; load D rows into registers ----
  float dq0[32], dq1[32];
  {
    float e0 = 0.f, e1 = 0.f;
    #pragma unroll 8
    for (int k = 0; k < 32; ++k) {
      float cl = SR[r*PA + k];               // C[r][k]
      e0 = fmaf(CQT[k*32 + q],      cl, e0); // CQ[q][k]
      e1 = fmaf(CQT[k*32 + q + 16], cl, e1);
    }
    EL[q*32 + r]      = e0 + Rg[q*32 + r];
    EL[(q+16)*32 + r] = e1 + Rg[(q+16)*32 + r];
    #pragma unroll
    for (int k = 0; k < 32; ++k) {
      dq0[k] = DLDS[q*PA + k];
      dq1[k] = DLDS[(q+16)*PA + k];
    }
  }
  __syncthreads();

  const int ro0 = q*ST + r;
  const int ro1 = (q+16)*ST + r;

  for (int t = 0; t < TT; ++t) {
    const long bt = btB + t;

    // ---- P1: T1 = A@Sigma, T1P = D@Sigma (Sigma sym: row-row dots);
    //          tails: mu_pred = A mu + B u ; residual = y - D mu - F u ----
    {
      float ta, tb, tc, td;
      dot32x4(SIG + r*ST, aq0, aq1, dq0, dq1, ta, tb, tc, td);
      T1[ro0] = ta; T1[ro1] = tb;
      T1P[ro0] = tc; T1P[ro1] = td;
      if (tid < 32) {
        float s = 0.f;
        #pragma unroll
        for (int k = 0; k < 32; ++k) s = fmaf(ALDS[tid*PA + k], mu_lds[k], s);
        #pragma unroll
        for (int k = 0; k < 16; ++k) s = fmaf(Bg[tid*16 + k], u_lds[k], s);
        mupred[tid] = s;
      } else if (tid >= 64 && tid < 96) {
        const int i = tid - 64;
        float s = y_lds[i];
        #pragma unroll
        for (int k = 0; k < 32; ++k) s = fmaf(-DLDS[i*PA + k], mu_lds[k], s);
        #pragma unroll
        for (int k = 0; k < 16; ++k) s = fmaf(-FL[i*FSTR + k], u_lds[k], s);
        T2T[32*ST + i] = s;
      }
    }
    __syncthreads();

    // ---- P2: SigP = T1@A^T + Q (sym trick) ; T2 = T1P@A^T + CQ (store T2T[col][row]) ;
    //          S = T1P@D^T + E (sym trick) ----
    {
      float p0, p1;
      dot32x2(T1 + r*ST, aq0, aq1, p0, p1);
      float t2a, t2b, sa, sb;
      dot32x4(T1P + r*ST, aq0, aq1, dq0, dq1, t2a, t2b, sa, sb);
      SIGP[ro0] = p0 + QL[q*32 + r];
      SIGP[ro1] = p1 + QL[(q+16)*32 + r];
      T2T[ro0] = t2a + CQT[q*32 + r];        // T2T[q][r] = T2[r][q]
      T2T[ro1] = t2b + CQT[(q+16)*32 + r];
      SR[ro0] = sa + EL[q*32 + r];
      SR[ro1] = sb + EL[(q+16)*32 + r];
    }
    __syncthreads();

    // ---- P3: wave0: parity-split Cholesky + fwd subst -> WT (HW-verified R6/R7);
    //          lane l = column c=(l&31), rows of parity hb=(l>>5).
    //          waves1-7: stream outputs + prefetch next y/u/mask ----
    if (tid < 64) {
      const int c  = tid & 31;
      const int hb = tid >> 5;          // 0 = even rows, 1 = odd rows
      const int side = hb << 5;         // bw source offset (per-lane)
      float w[16], rr[16], rz[16];      // rows 2s+hb of: S col c, RHS col c, residual
      #pragma unroll
      for (int s4 = 0; s4 < 16; s4 += 2) {
        float4 vw = ld4(SR  + c*ST  + s4*2);
        float4 vr = ld4(T2T + c*ST  + s4*2);
        float4 vz = ld4(T2T + 32*ST + s4*2);
        w[s4]   = hb ? vw.y : vw.x;  w[s4+1]  = hb ? vw.w : vw.z;
        rr[s4]  = hb ? vr.y : vr.x;  rr[s4+1] = hb ? vr.w : vr.z;
        rz[s4]  = hb ? vz.y : vz.x;  rz[s4+1] = hb ? vz.w : vz.z;
      }
      #pragma unroll
      for (int j = 0; j < 32; ++j) {
        const int pj = j & 1, sj = j >> 1;
        // pivot d = M[j][j]: column j's parity-pj holder = lane j + 32*pj
        float d   = rdlane(w[sj], j | (pj << 5));
        float sjv = RSQF(d);
        float s2  = sjv * sjv;
        // row-j values of my column (and residual): holder lane = c + 32*pj (per-lane src)
        float mjw = __shfl(w[sj],  c | (pj << 5));
        float mjr = __shfl(rr[sj], c | (pj << 5));
        float mjz = __shfl(rz[sj], c | (pj << 5));
        float gw = s2 * mjw, gr = s2 * mjr, gz = s2 * mjz;
        if (hb == 0) {
          WT[c*ST + j] = mjr * sjv;           // z[j] for column c
          if (c == 0) WT[32*ST + j] = mjz * sjv;  // z[j] for residual
        }
        // trailing update: rows 2s+hb, s >= sj covers all i>j of my parity;
        // s==sj may touch row <= j: harmless (those rows are never read again).
        #pragma unroll
        for (int s = sj; s < 16; ++s) {
          float bw = __shfl(w[s], j + side);  // M[i][j] from column-j's my-parity holder
          w[s]  = fmaf(-bw, gw, w[s]);
          rr[s] = fmaf(-bw, gr, rr[s]);
          rz[s] = fmaf(-bw, gz, rz[s]);
        }
      }
    } else {
      const int u = tid - 64;                    // 0..447
      if (u < 256) {
        st4(out + o_Sp + bt*1024 + u*4, ld4(SIGP + (u>>3)*ST + (u&7)*4));
      } else if (t > 0) {
        const int q2 = u - 256;                  // 0..191
        st4(out + o_Sf + (bt-1)*1024 + q2*4, ld4(SIG + (q2>>3)*ST + (q2&7)*4));
      }
      if (u < 64 && t > 0) {
        const int q2 = u + 192;                  // 192..255
        st4(out + o_Sf + (bt-1)*1024 + q2*4, ld4(SIG + (q2>>3)*ST + (q2&7)*4));
      }
      if (tid >= 64 && tid < 96)  out[o_mp + bt*32 + (tid-64)] = mupred[tid-64];
      if (t > 0 && tid >= 96 && tid < 128) out[(bt-1)*32 + (tid-96)] = mu_lds[tid-96];
      if (t < TT-1) {                            // prefetch t+1 (hidden under Cholesky)
        if (tid >= 128 && tid < 144) u_lds[tid-128] = Ug[(bt+1)*16 + (tid-128)];
        if (tid >= 160 && tid < 192) y_lds[tid-160] = Yg[(bt+1)*32 + (tid-160)];
        if (tid == 200) mlds[(t+1)&1] = Mg[bt+1];
      }
    }
    __syncthreads();

    // ---- P4 (R5 form): G[i][j] = dot(WTrow_i, WTrow_j);
    //          Sigma' = SigP + (m^2-2m) G ; mu' = mu_pred + m*dot(WTrow_i, WTrow_32) ----
    {
      const float m = mlds[t&1];
      const float coefS = fmaf(m, m, -2.f*m);   // m^2 - 2m
      float rv[32];
      #pragma unroll
      for (int k = 0; k < 32; k += 4) {
        float4 v = ld4(WT + r*ST + k);
        rv[k] = v.x; rv[k+1] = v.y; rv[k+2] = v.z; rv[k+3] = v.w;
      }
      float ga = dot32r(WT + q*ST, rv);
      float gb = dot32r(WT + (q+16)*ST, rv);
      SIG[ro0] = fmaf(coefS, ga, SIGP[ro0]);
      SIG[ro1] = fmaf(coefS, gb, SIGP[ro1]);
      if (tid < 32) {
        float sacc = dot32rr(WT + tid*ST, WT + 32*ST);
        mu_lds[tid] = fmaf(m, sacc, mupred[tid]);
      }
    }
    __syncthreads();
  }

  // ---- final filtered outputs for t = T-1 ----
  {
    const long bt = btB + TT - 1;
    if (tid < 256)
      st4(out + o_Sf + bt*1024 + tid*4, ld4(SIG + (tid>>3)*ST + (tid&7)*4));
    if (tid >= 480)
      out[bt*32 + (tid - 480)] = mu_lds[tid - 480];
  }
}

extern "C" void kernel_launch(void* const* d_in, const int* in_sizes, int n_in,
                              void* d_out, int out_size, void* d_ws, size_t ws_size,
                              hipStream_t stream) {
  const float* Y   = (const float*)d_in[0];
  const float* U   = (const float*)d_in[1];
  const float* Mk  = (const float*)d_in[2];
  const float* A   = (const float*)d_in[3];
  const float* Bm  = (const float*)d_in[4];
  const float* C   = (const float*)d_in[5];
  const float* mu0 = (const float*)d_in[6];
  const float* S0  = (const float*)d_in[7];
  const float* Q   = (const float*)d_in[8];
  const float* R   = (const float*)d_in[9];
  int Bsz = in_sizes[2] / TT;
  kf_kernel<<<Bsz, 512, 0, stream>>>(Y, U, Mk, A, Bm, C, mu0, S0, Q, R,
                                     (float*)d_out, Bsz);
}

// Round 11
// 5220.868 us; speedup vs baseline: 1.2236x; 1.2236x over previous
//
#include <hip/hip_runtime.h>
#include <math.h>

#define TT 200
#define ST 36    // padded stride (mult of 4): rows 16B-aligned
#define PA 33    // stride for scalar-read LDS copies (A, D)
#define FSTR 17  // stride for F (32x16)

__device__ __forceinline__ float rdlane(float v, int l) {
  return __int_as_float(__builtin_amdgcn_readlane(__float_as_int(v), l));
}

#if __has_builtin(__builtin_amdgcn_rsqf)
#define RSQF(x) __builtin_amdgcn_rsqf(x)
#else
#define RSQF(x) (1.0f / sqrtf(x))
#endif

__device__ __forceinline__ float4 ld4(const float* p) { return *(const float4*)p; }
__device__ __forceinline__ void st4(float* p, float4 v) { *(float4*)p = v; }

// dot of a 32-float LDS row with a register-resident row
__device__ __forceinline__ float dot32r(const float* __restrict__ row, const float (&a)[32]) {
  float s0 = 0.f, s1 = 0.f;
  #pragma unroll
  for (int k = 0; k < 32; k += 8) {
    float4 v0 = ld4(row + k);
    float4 v1 = ld4(row + k + 4);
    s0 = fmaf(a[k+0], v0.x, s0); s0 = fmaf(a[k+1], v0.y, s0);
    s0 = fmaf(a[k+2], v0.z, s0); s0 = fmaf(a[k+3], v0.w, s0);
    s1 = fmaf(a[k+4], v1.x, s1); s1 = fmaf(a[k+5], v1.y, s1);
    s1 = fmaf(a[k+6], v1.z, s1); s1 = fmaf(a[k+7], v1.w, s1);
  }
  return s0 + s1;
}

// one LDS row-read, two register rows -> two dots
__device__ __forceinline__ void dot32x2(const float* __restrict__ row,
                                        const float (&a)[32], const float (&b)[32],
                                        float& oa, float& ob) {
  float a0=0.f, a1=0.f, b0=0.f, b1=0.f;
  #pragma unroll
  for (int k = 0; k < 32; k += 8) {
    float4 v0 = ld4(row + k);
    float4 v1 = ld4(row + k + 4);
    a0 = fmaf(a[k+0], v0.x, a0); a1 = fmaf(a[k+1], v0.y, a1);
    a0 = fmaf(a[k+2], v0.z, a0); a1 = fmaf(a[k+3], v0.w, a1);
    b0 = fmaf(b[k+0], v0.x, b0); b1 = fmaf(b[k+1], v0.y, b1);
    b0 = fmaf(b[k+2], v0.z, b0); b1 = fmaf(b[k+3], v0.w, b1);
    a0 = fmaf(a[k+4], v1.x, a0); a1 = fmaf(a[k+5], v1.y, a1);
    a0 = fmaf(a[k+6], v1.z, a0); a1 = fmaf(a[k+7], v1.w, a1);
    b0 = fmaf(b[k+4], v1.x, b0); b1 = fmaf(b[k+5], v1.y, b1);
    b0 = fmaf(b[k+6], v1.z, b0); b1 = fmaf(b[k+7], v1.w, b1);
  }
  oa = a0 + a1; ob = b0 + b1;
}

// one LDS row-read, four register rows -> four dots
__device__ __forceinline__ void dot32x4(const float* __restrict__ row,
    const float (&a)[32], const float (&b)[32], const float (&c)[32], const float (&d)[32],
    float& oa, float& ob, float& oc, float& od) {
  float sa=0.f, sb=0.f, sc=0.f, sd=0.f;
  #pragma unroll
  for (int k = 0; k < 32; k += 4) {
    float4 v = ld4(row + k);
    sa = fmaf(a[k+0], v.x, sa); sb = fmaf(b[k+0], v.x, sb);
    sc = fmaf(c[k+0], v.x, sc); sd = fmaf(d[k+0], v.x, sd);
    sa = fmaf(a[k+1], v.y, sa); sb = fmaf(b[k+1], v.y, sb);
    sc = fmaf(c[k+1], v.y, sc); sd = fmaf(d[k+1], v.y, sd);
    sa = fmaf(a[k+2], v.z, sa); sb = fmaf(b[k+2], v.z, sb);
    sc = fmaf(c[k+2], v.z, sc); sd = fmaf(d[k+2], v.z, sd);
    sa = fmaf(a[k+3], v.w, sa); sb = fmaf(b[k+3], v.w, sb);
    sc = fmaf(c[k+3], v.w, sc); sd = fmaf(d[k+3], v.w, sd);
  }
  oa = sa; ob = sb; oc = sc; od = sd;
}

// dot of two 32-float LDS rows
__device__ __forceinline__ float dot32rr(const float* __restrict__ ra, const float* __restrict__ rb) {
  float s0 = 0.f, s1 = 0.f;
  #pragma unroll
  for (int k = 0; k < 32; k += 8) {
    float4 x0 = ld4(ra + k), x1 = ld4(ra + k + 4);
    float4 y0 = ld4(rb + k), y1 = ld4(rb + k + 4);
    s0 = fmaf(x0.x, y0.x, s0); s0 = fmaf(x0.y, y0.y, s0);
    s0 = fmaf(x0.z, y0.z, s0); s0 = fmaf(x0.w, y0.w, s0);
    s1 = fmaf(x1.x, y1.x, s1); s1 = fmaf(x1.y, y1.y, s1);
    s1 = fmaf(x1.z, y1.z, s1); s1 = fmaf(x1.w, y1.w, s1);
  }
  return s0 + s1;
}

// ---- parity-split Cholesky, template-forced STATIC indexing ----
// R6/R7/R10 lesson: the #pragma-unroll form left w[sj] runtime-indexed
// (compiler declined the 32x unroll) -> arrays in memory scratch (rule #20),
// FETCH_SIZE 5 GB. constexpr indices guarantee register placement.
template<int J>
__device__ __forceinline__ void chol_body(float (&w)[16], float (&rr)[16], float (&rz)[16],
                                          const int c, const int hb, const int side,
                                          float* __restrict__ WT) {
  constexpr int pj = J & 1;
  constexpr int sj = J >> 1;
  float d   = rdlane(w[sj], J | (pj << 5));   // pivot M[J][J] (wave-uniform)
  float sjv = RSQF(d);
  float s2  = sjv * sjv;
  // row-J values of my column (and residual): holder lane = c + 32*pj
  float mjw = __shfl(w[sj],  c | (pj << 5));
  float mjr = __shfl(rr[sj], c | (pj << 5));
  float mjz = __shfl(rz[sj], c | (pj << 5));
  float gw = s2 * mjw, gr = s2 * mjr, gz = s2 * mjz;
  if (hb == 0) {
    WT[c*ST + J] = mjr * sjv;               // z[J] for column c
    if (c == 0) WT[32*ST + J] = mjz * sjv;  // z[J] for residual
  }
  // trailing update: rows 2s+hb, s >= sj covers all i>J of my parity;
  // s==sj may touch row <= J: harmless (those rows are never read again).
  #pragma unroll
  for (int s = sj; s < 16; ++s) {           // sj constexpr -> static after unroll
    float bw = __shfl(w[s], J + side);      // M[i][J] from column-J's my-parity holder
    w[s]  = fmaf(-bw, gw, w[s]);
    rr[s] = fmaf(-bw, gr, rr[s]);
    rz[s] = fmaf(-bw, gz, rz[s]);
  }
}

template<int J>
__device__ __forceinline__ void chol_all(float (&w)[16], float (&rr)[16], float (&rz)[16],
                                         const int c, const int hb, const int side,
                                         float* __restrict__ WT) {
  if constexpr (J < 32) {
    chol_body<J>(w, rr, rz, c, hb, side, WT);
    chol_all<J + 1>(w, rr, rz, c, hb, side, WT);
  }
}

// launch_bounds(512, 1): grid == 256 == #CUs -> 1 block/CU regardless; no
// reason to constrain the allocator (R10: bound value doesn't affect VGPRs).
__global__ void __launch_bounds__(512, 1) kf_kernel(
    const float* __restrict__ Yg, const float* __restrict__ Ug,
    const float* __restrict__ Mg, const float* __restrict__ Ag,
    const float* __restrict__ Bg, const float* __restrict__ Cg,
    const float* __restrict__ mu0g, const float* __restrict__ S0g,
    const float* __restrict__ Qg, const float* __restrict__ Rg,
    float* __restrict__ out, int Bsz)
{
  __shared__ __align__(16) float SIG[32*ST];    // Sigma filtered (symmetric)
  __shared__ __align__(16) float T1[32*ST];     // A @ Sigma
  __shared__ __align__(16) float T1P[32*ST];    // D @ Sigma  (D = C@A)
  __shared__ __align__(16) float SIGP[32*ST];   // Sigma_pred
  __shared__ __align__(16) float T2T[33*ST];    // T2T[j][i] = T2[i][j]; row 32 = residual
  __shared__ __align__(16) float SR[32*ST];     // S (row ~= col by symmetry)
  __shared__ __align__(16) float WT[33*ST];     // WT[cc][j] = W[j][cc]; row 32 = z
  __shared__ __align__(16) float QL[1024];      // Q
  __shared__ __align__(16) float CQT[1024];     // CQT[q*32+r] = (C@Q)[r][q]
  __shared__ __align__(16) float EL[1024];      // E = C@Q@C^T + R
  __shared__ float ALDS[32*PA];                 // A rows, scalar-read
  __shared__ float DLDS[32*PA];                 // D rows, scalar-read
  __shared__ float FL[32*FSTR];                 // F = C@B (32x16)
  __shared__ float u_lds[16], y_lds[32], mupred[32], mu_lds[32], mlds[2];

  const int tid = threadIdx.x;
  const int q = tid >> 5;           // 0..15 -> owns output rows q, q+16
  const int r = tid & 31;           // output column
  const int b = blockIdx.x;
  const long btB = (long)b * TT;

  const long o_Sf = (long)Bsz * TT * 32;
  const long o_mp = o_Sf + (long)Bsz * TT * 32 * 32;
  const long o_Sp = o_mp + (long)Bsz * TT * 32;

  // ---- init 0: stage constants. C temporarily lives in SR (scalar copy, stride PA) ----
  for (int e = tid; e < 1024; e += 512) {
    int i = e >> 5, k = e & 31;
    ALDS[i*PA + k] = Ag[e];
    SR[i*PA + k]   = Cg[e];     // CL alias (clobbered by t-loop later)
    QL[e] = Qg[e];
    SIG[i*ST + k] = S0g[e];
  }
  if (tid < 32) mu_lds[tid] = mu0g[tid];
  if (tid < 16) u_lds[tid] = Ug[btB*16 + tid];
  if (tid >= 64 && tid < 96) y_lds[tid-64] = Yg[btB*32 + (tid-64)];
  if (tid == 224) mlds[0] = Mg[btB];

  // persistent register rows: A rows q, q+16
  float aq0[32], aq1[32];
  #pragma unroll
  for (int k = 0; k < 32; k += 4) {
    float4 v;
    v = ld4(Ag + q*32 + k);      aq0[k]=v.x; aq0[k+1]=v.y; aq0[k+2]=v.z; aq0[k+3]=v.w;
    v = ld4(Ag + (q+16)*32 + k); aq1[k]=v.x; aq1[k+1]=v.y; aq1[k+2]=v.z; aq1[k+3]=v.w;
  }
  __syncthreads();

  // ---- init 1: D = C@A, CQT[q*32+r] = (C@Q)[r][q], F = C@B ----
  {
    float d0 = 0.f, d1 = 0.f, x0 = 0.f, x1 = 0.f;
    #pragma unroll 8
    for (int k = 0; k < 32; ++k) {
      float al = ALDS[k*PA + r];
      d0 = fmaf(SR[q*PA + k],      al, d0);
      d1 = fmaf(SR[(q+16)*PA + k], al, d1);
      float cl = SR[r*PA + k];
      x0 = fmaf(cl, QL[k*32 + q],      x0);
      x1 = fmaf(cl, QL[k*32 + q + 16], x1);
    }
    DLDS[q*PA + r] = d0; DLDS[(q+16)*PA + r] = d1;
    CQT[q*32 + r] = x0;  CQT[(q+16)*32 + r] = x1;
    const int fi = tid >> 4, fj = tid & 15;   // 32x16 = 512 outputs
    float f = 0.f;
    #pragma unroll 8
    for (int k = 0; k < 32; ++k) f = fmaf(SR[fi*PA + k], Bg[k*16 + fj], f);
    FL[fi*FSTR + fj] = f;
  }
  __syncthreads();

  // ---- init 2: E = CQ@C^T + R ; load D rows into registers ----
  float dq0[32], dq1[32];
  {
    float e0 = 0.f, e1 = 0.f;
    #pragma unroll 8
    for (int k = 0; k < 32; ++k) {
      float cl = SR[r*PA + k];               // C[r][k]
      e0 = fmaf(CQT[k*32 + q],      cl, e0); // CQ[q][k]
      e1 = fmaf(CQT[k*32 + q + 16], cl, e1);
    }
    EL[q*32 + r]      = e0 + Rg[q*32 + r];
    EL[(q+16)*32 + r] = e1 + Rg[(q+16)*32 + r];
    #pragma unroll
    for (int k = 0; k < 32; ++k) {
      dq0[k] = DLDS[q*PA + k];
      dq1[k] = DLDS[(q+16)*PA + k];
    }
  }
  __syncthreads();

  const int ro0 = q*ST + r;
  const int ro1 = (q+16)*ST + r;

  for (int t = 0; t < TT; ++t) {
    const long bt = btB + t;

    // ---- P1: T1 = A@Sigma, T1P = D@Sigma (Sigma sym: row-row dots);
    //          tails: mu_pred = A mu + B u ; residual = y - D mu - F u ----
    {
      float ta, tb, tc, td;
      dot32x4(SIG + r*ST, aq0, aq1, dq0, dq1, ta, tb, tc, td);
      T1[ro0] = ta; T1[ro1] = tb;
      T1P[ro0] = tc; T1P[ro1] = td;
      if (tid < 32) {
        float s = 0.f;
        #pragma unroll
        for (int k = 0; k < 32; ++k) s = fmaf(ALDS[tid*PA + k], mu_lds[k], s);
        #pragma unroll
        for (int k = 0; k < 16; ++k) s = fmaf(Bg[tid*16 + k], u_lds[k], s);
        mupred[tid] = s;
      } else if (tid >= 64 && tid < 96) {
        const int i = tid - 64;
        float s = y_lds[i];
        #pragma unroll
        for (int k = 0; k < 32; ++k) s = fmaf(-DLDS[i*PA + k], mu_lds[k], s);
        #pragma unroll
        for (int k = 0; k < 16; ++k) s = fmaf(-FL[i*FSTR + k], u_lds[k], s);
        T2T[32*ST + i] = s;
      }
    }
    __syncthreads();

    // ---- P2: SigP = T1@A^T + Q (sym trick) ; T2 = T1P@A^T + CQ (store T2T[col][row]) ;
    //          S = T1P@D^T + E (sym trick) ----
    {
      float p0, p1;
      dot32x2(T1 + r*ST, aq0, aq1, p0, p1);
      float t2a, t2b, sa, sb;
      dot32x4(T1P + r*ST, aq0, aq1, dq0, dq1, t2a, t2b, sa, sb);
      SIGP[ro0] = p0 + QL[q*32 + r];
      SIGP[ro1] = p1 + QL[(q+16)*32 + r];
      T2T[ro0] = t2a + CQT[q*32 + r];        // T2T[q][r] = T2[r][q]
      T2T[ro1] = t2b + CQT[(q+16)*32 + r];
      SR[ro0] = sa + EL[q*32 + r];
      SR[ro1] = sb + EL[(q+16)*32 + r];
    }
    __syncthreads();

    // ---- P3: wave0: parity-split Cholesky + fwd subst -> WT (template-static);
    //          lane l = column c=(l&31), rows of parity hb=(l>>5).
    //          waves1-7: stream outputs + prefetch next y/u/mask ----
    if (tid < 64) {
      const int c  = tid & 31;
      const int hb = tid >> 5;          // 0 = even rows, 1 = odd rows
      const int side = hb << 5;         // bw source offset (per-lane)
      float w[16], rr[16], rz[16];      // rows 2s+hb of: S col c, RHS col c, residual
      #pragma unroll
      for (int s4 = 0; s4 < 16; s4 += 2) {
        float4 vw = ld4(SR  + c*ST  + s4*2);
        float4 vr = ld4(T2T + c*ST  + s4*2);
        float4 vz = ld4(T2T + 32*ST + s4*2);
        w[s4]   = hb ? vw.y : vw.x;  w[s4+1]  = hb ? vw.w : vw.z;
        rr[s4]  = hb ? vr.y : vr.x;  rr[s4+1] = hb ? vr.w : vr.z;
        rz[s4]  = hb ? vz.y : vz.x;  rz[s4+1] = hb ? vz.w : vz.z;
      }
      chol_all<0>(w, rr, rz, c, hb, side, WT);
    } else {
      const int u = tid - 64;                    // 0..447
      if (u < 256) {
        st4(out + o_Sp + bt*1024 + u*4, ld4(SIGP + (u>>3)*ST + (u&7)*4));
      } else if (t > 0) {
        const int q2 = u - 256;                  // 0..191
        st4(out + o_Sf + (bt-1)*1024 + q2*4, ld4(SIG + (q2>>3)*ST + (q2&7)*4));
      }
      if (u < 64 && t > 0) {
        const int q2 = u + 192;                  // 192..255
        st4(out + o_Sf + (bt-1)*1024 + q2*4, ld4(SIG + (q2>>3)*ST + (q2&7)*4));
      }
      if (tid >= 64 && tid < 96)  out[o_mp + bt*32 + (tid-64)] = mupred[tid-64];
      if (t > 0 && tid >= 96 && tid < 128) out[(bt-1)*32 + (tid-96)] = mu_lds[tid-96];
      if (t < TT-1) {                            // prefetch t+1 (hidden under Cholesky)
        if (tid >= 128 && tid < 144) u_lds[tid-128] = Ug[(bt+1)*16 + (tid-128)];
        if (tid >= 160 && tid < 192) y_lds[tid-160] = Yg[(bt+1)*32 + (tid-160)];
        if (tid == 200) mlds[(t+1)&1] = Mg[bt+1];
      }
    }
    __syncthreads();

    // ---- P4 (R5 form): G[i][j] = dot(WTrow_i, WTrow_j);
    //          Sigma' = SigP + (m^2-2m) G ; mu' = mu_pred + m*dot(WTrow_i, WTrow_32) ----
    {
      const float m = mlds[t&1];
      const float coefS = fmaf(m, m, -2.f*m);   // m^2 - 2m
      float rv[32];
      #pragma unroll
      for (int k = 0; k < 32; k += 4) {
        float4 v = ld4(WT + r*ST + k);
        rv[k] = v.x; rv[k+1] = v.y; rv[k+2] = v.z; rv[k+3] = v.w;
      }
      float ga = dot32r(WT + q*ST, rv);
      float gb = dot32r(WT + (q+16)*ST, rv);
      SIG[ro0] = fmaf(coefS, ga, SIGP[ro0]);
      SIG[ro1] = fmaf(coefS, gb, SIGP[ro1]);
      if (tid < 32) {
        float sacc = dot32rr(WT + tid*ST, WT + 32*ST);
        mu_lds[tid] = fmaf(m, sacc, mupred[tid]);
      }
    }
    __syncthreads();
  }

  // ---- final filtered outputs for t = T-1 ----
  {
    const long bt = btB + TT - 1;
    if (tid < 256)
      st4(out + o_Sf + bt*1024 + tid*4, ld4(SIG + (tid>>3)*ST + (tid&7)*4));
    if (tid >= 480)
      out[bt*32 + (tid - 480)] = mu_lds[tid - 480];
  }
}

extern "C" void kernel_launch(void* const* d_in, const int* in_sizes, int n_in,
                              void* d_out, int out_size, void* d_ws, size_t ws_size,
                              hipStream_t stream) {
  const float* Y   = (const float*)d_in[0];
  const float* U   = (const float*)d_in[1];
  const float* Mk  = (const float*)d_in[2];
  const float* A   = (const float*)d_in[3];
  const float* Bm  = (const float*)d_in[4];
  const float* C   = (const float*)d_in[5];
  const float* mu0 = (const float*)d_in[6];
  const float* S0  = (const float*)d_in[7];
  const float* Q   = (const float*)d_in[8];
  const float* R   = (const float*)d_in[9];
  int Bsz = in_sizes[2] / TT;
  kf_kernel<<<Bsz, 512, 0, stream>>>(Y, U, Mk, A, Bm, C, mu0, S0, Q, R,
                                     (float*)d_out, Bsz);
}

// Round 13
// 1606.819 us; speedup vs baseline: 3.9758x; 3.2492x over previous
//
#include <hip/hip_runtime.h>
#include <math.h>

#define TT 200
#define ST 36    // padded stride (mult of 4): rows 16B-aligned
#define PA 33    // stride for scalar-read LDS copies (A, D)
#define FSTR 17  // stride for F (32x16), odd -> conflict-free per-lane row reads

__device__ __forceinline__ float rdlane(float v, int l) {
  return __int_as_float(__builtin_amdgcn_readlane(__float_as_int(v), l));
}

#if __has_builtin(__builtin_amdgcn_rsqf)
#define RSQF(x) __builtin_amdgcn_rsqf(x)
#else
#define RSQF(x) (1.0f / sqrtf(x))
#endif

__device__ __forceinline__ float4 ld4(const float* p) { return *(const float4*)p; }
__device__ __forceinline__ void st4(float* p, float4 v) { *(float4*)p = v; }

// dot of a 32-float LDS row with a register-resident row
__device__ __forceinline__ float dot32r(const float* __restrict__ row, const float (&a)[32]) {
  float s0 = 0.f, s1 = 0.f;
  #pragma unroll
  for (int k = 0; k < 32; k += 8) {
    float4 v0 = ld4(row + k);
    float4 v1 = ld4(row + k + 4);
    s0 = fmaf(a[k+0], v0.x, s0); s0 = fmaf(a[k+1], v0.y, s0);
    s0 = fmaf(a[k+2], v0.z, s0); s0 = fmaf(a[k+3], v0.w, s0);
    s1 = fmaf(a[k+4], v1.x, s1); s1 = fmaf(a[k+5], v1.y, s1);
    s1 = fmaf(a[k+6], v1.z, s1); s1 = fmaf(a[k+7], v1.w, s1);
  }
  return s0 + s1;
}

// one LDS row-read, two register rows -> two dots
__device__ __forceinline__ void dot32x2(const float* __restrict__ row,
                                        const float (&a)[32], const float (&b)[32],
                                        float& oa, float& ob) {
  float a0=0.f, a1=0.f, b0=0.f, b1=0.f;
  #pragma unroll
  for (int k = 0; k < 32; k += 8) {
    float4 v0 = ld4(row + k);
    float4 v1 = ld4(row + k + 4);
    a0 = fmaf(a[k+0], v0.x, a0); a1 = fmaf(a[k+1], v0.y, a1);
    a0 = fmaf(a[k+2], v0.z, a0); a1 = fmaf(a[k+3], v0.w, a1);
    b0 = fmaf(b[k+0], v0.x, b0); b1 = fmaf(b[k+1], v0.y, b1);
    b0 = fmaf(b[k+2], v0.z, b0); b1 = fmaf(b[k+3], v0.w, b1);
    a0 = fmaf(a[k+4], v1.x, a0); a1 = fmaf(a[k+5], v1.y, a1);
    a0 = fmaf(a[k+6], v1.z, a0); a1 = fmaf(a[k+7], v1.w, a1);
    b0 = fmaf(b[k+4], v1.x, b0); b1 = fmaf(b[k+5], v1.y, b1);
    b0 = fmaf(b[k+6], v1.z, b0); b1 = fmaf(b[k+7], v1.w, b1);
  }
  oa = a0 + a1; ob = b0 + b1;
}

// one LDS row-read, four register rows -> four dots
__device__ __forceinline__ void dot32x4(const float* __restrict__ row,
    const float (&a)[32], const float (&b)[32], const float (&c)[32], const float (&d)[32],
    float& oa, float& ob, float& oc, float& od) {
  float sa=0.f, sb=0.f, sc=0.f, sd=0.f;
  #pragma unroll
  for (int k = 0; k < 32; k += 4) {
    float4 v = ld4(row + k);
    sa = fmaf(a[k+0], v.x, sa); sb = fmaf(b[k+0], v.x, sb);
    sc = fmaf(c[k+0], v.x, sc); sd = fmaf(d[k+0], v.x, sd);
    sa = fmaf(a[k+1], v.y, sa); sb = fmaf(b[k+1], v.y, sb);
    sc = fmaf(c[k+1], v.y, sc); sd = fmaf(d[k+1], v.y, sd);
    sa = fmaf(a[k+2], v.z, sa); sb = fmaf(b[k+2], v.z, sb);
    sc = fmaf(c[k+2], v.z, sc); sd = fmaf(d[k+2], v.z, sd);
    sa = fmaf(a[k+3], v.w, sa); sb = fmaf(b[k+3], v.w, sb);
    sc = fmaf(c[k+3], v.w, sc); sd = fmaf(d[k+3], v.w, sd);
  }
  oa = sa; ob = sb; oc = sc; od = sd;
}

// dot of two 32-float LDS rows
__device__ __forceinline__ float dot32rr(const float* __restrict__ ra, const float* __restrict__ rb) {
  float s0 = 0.f, s1 = 0.f;
  #pragma unroll
  for (int k = 0; k < 32; k += 8) {
    float4 x0 = ld4(ra + k), x1 = ld4(ra + k + 4);
    float4 y0 = ld4(rb + k), y1 = ld4(rb + k + 4);
    s0 = fmaf(x0.x, y0.x, s0); s0 = fmaf(x0.y, y0.y, s0);
    s0 = fmaf(x0.z, y0.z, s0); s0 = fmaf(x0.w, y0.w, s0);
    s1 = fmaf(x1.x, y1.x, s1); s1 = fmaf(x1.y, y1.y, s1);
    s1 = fmaf(x1.z, y1.z, s1); s1 = fmaf(x1.w, y1.w, s1);
  }
  return s0 + s1;
}

// NOTE: this exact configuration (serial in-register chol, (512,2) bounds)
// is the allocator-stable point: measured 1322 us, FETCH 7.1 MB. The
// parity-split chol (R6/R7/R11, 3 formulations incl. template-static)
// spills to scratch (FETCH 5+ GB) regardless of launch bounds. Chol frozen.
__global__ void __launch_bounds__(512, 2) kf_kernel(
    const float* __restrict__ Yg, const float* __restrict__ Ug,
    const float* __restrict__ Mg, const float* __restrict__ Ag,
    const float* __restrict__ Bg, const float* __restrict__ Cg,
    const float* __restrict__ mu0g, const float* __restrict__ S0g,
    const float* __restrict__ Qg, const float* __restrict__ Rg,
    float* __restrict__ out, int Bsz)
{
  __shared__ __align__(16) float SIG[32*ST];    // Sigma filtered (symmetric)
  __shared__ __align__(16) float T1[32*ST];     // A @ Sigma
  __shared__ __align__(16) float T1P[32*ST];    // D @ Sigma  (D = C@A)
  __shared__ __align__(16) float SIGP[32*ST];   // Sigma_pred
  __shared__ __align__(16) float T2T[33*ST];    // T2T[j][i] = T2[i][j]; row 32 = residual
  __shared__ __align__(16) float SR[32*ST];     // S (row ~= col by symmetry)
  __shared__ __align__(16) float WT[33*ST];     // WT[cc][j] = W[j][cc]; row 32 = z
  __shared__ __align__(16) float QL[1024];      // Q
  __shared__ __align__(16) float CQT[1024];     // CQT[q*32+r] = (C@Q)[r][q]
  __shared__ __align__(16) float EL[1024];      // E = C@Q@C^T + R
  __shared__ float ALDS[32*PA];                 // A rows, scalar-read
  __shared__ float DLDS[32*PA];                 // D rows, scalar-read
  __shared__ float FL[32*FSTR];                 // F = C@B (32x16)
  __shared__ float u_lds[16], y_lds[32], mupred[32], mu_lds[32], mlds[2];

  const int tid = threadIdx.x;
  const int q = tid >> 5;           // 0..15 -> owns output rows q, q+16
  const int r = tid & 31;           // output column
  const int b = blockIdx.x;
  const long btB = (long)b * TT;

  const long o_Sf = (long)Bsz * TT * 32;
  const long o_mp = o_Sf + (long)Bsz * TT * 32 * 32;
  const long o_Sp = o_mp + (long)Bsz * TT * 32;

  // ---- init 0: stage constants. C temporarily lives in SR (scalar copy, stride PA) ----
  for (int e = tid; e < 1024; e += 512) {
    int i = e >> 5, k = e & 31;
    ALDS[i*PA + k] = Ag[e];
    SR[i*PA + k]   = Cg[e];     // CL alias (clobbered by t-loop later)
    QL[e] = Qg[e];
    SIG[i*ST + k] = S0g[e];
  }
  if (tid < 32) mu_lds[tid] = mu0g[tid];
  if (tid < 16) u_lds[tid] = Ug[btB*16 + tid];
  if (tid >= 64 && tid < 96) y_lds[tid-64] = Yg[btB*32 + (tid-64)];
  if (tid == 224) mlds[0] = Mg[btB];

  // persistent register rows: A rows q, q+16
  float aq0[32], aq1[32];
  #pragma unroll
  for (int k = 0; k < 32; k += 4) {
    float4 v;
    v = ld4(Ag + q*32 + k);      aq0[k]=v.x; aq0[k+1]=v.y; aq0[k+2]=v.z; aq0[k+3]=v.w;
    v = ld4(Ag + (q+16)*32 + k); aq1[k]=v.x; aq1[k+1]=v.y; aq1[k+2]=v.z; aq1[k+3]=v.w;
  }
  __syncthreads();

  // ---- init 1: D = C@A, CQT[q*32+r] = (C@Q)[r][q], F = C@B ----
  {
    float d0 = 0.f, d1 = 0.f, x0 = 0.f, x1 = 0.f;
    #pragma unroll 8
    for (int k = 0; k < 32; ++k) {
      float al = ALDS[k*PA + r];
      d0 = fmaf(SR[q*PA + k],      al, d0);
      d1 = fmaf(SR[(q+16)*PA + k], al, d1);
      float cl = SR[r*PA + k];
      x0 = fmaf(cl, QL[k*32 + q],      x0);
      x1 = fmaf(cl, QL[k*32 + q + 16], x1);
    }
    DLDS[q*PA + r] = d0; DLDS[(q+16)*PA + r] = d1;
    CQT[q*32 + r] = x0;  CQT[(q+16)*32 + r] = x1;
    const int fi = tid >> 4, fj = tid & 15;   // 32x16 = 512 outputs
    float f = 0.f;
    #pragma unroll 8
    for (int k = 0; k < 32; ++k) f = fmaf(SR[fi*PA + k], Bg[k*16 + fj], f);
    FL[fi*FSTR + fj] = f;
  }
  __syncthreads();

  // ---- init 2: E = CQ@C^T + R ; load D rows into registers ----
  float dq0[32], dq1[32];
  {
    float e0 = 0.f, e1 = 0.f;
    #pragma unroll 8
    for (int k = 0; k < 32; ++k) {
      float cl = SR[r*PA + k];               // C[r][k]
      e0 = fmaf(CQT[k*32 + q],      cl, e0); // CQ[q][k]
      e1 = fmaf(CQT[k*32 + q + 16], cl, e1);
    }
    EL[q*32 + r]      = e0 + Rg[q*32 + r];
    EL[(q+16)*32 + r] = e1 + Rg[(q+16)*32 + r];
    #pragma unroll
    for (int k = 0; k < 32; ++k) {
      dq0[k] = DLDS[q*PA + k];
      dq1[k] = DLDS[(q+16)*PA + k];
    }
  }
  __syncthreads();

  const int ro0 = q*ST + r;
  const int ro1 = (q+16)*ST + r;

  for (int t = 0; t < TT; ++t) {
    const long bt = btB + t;

    // ---- P1: T1 = A@Sigma, T1P = D@Sigma (Sigma sym: row-row dots);
    //          tails: mu_pred = A mu + B u ; residual = y - D mu - F u ----
    {
      float ta, tb, tc, td;
      dot32x4(SIG + r*ST, aq0, aq1, dq0, dq1, ta, tb, tc, td);
      T1[ro0] = ta; T1[ro1] = tb;
      T1P[ro0] = tc; T1P[ro1] = td;
      if (tid < 32) {
        float s = 0.f;
        #pragma unroll
        for (int k = 0; k < 32; ++k) s = fmaf(ALDS[tid*PA + k], mu_lds[k], s);
        #pragma unroll
        for (int k = 0; k < 16; ++k) s = fmaf(Bg[tid*16 + k], u_lds[k], s);
        mupred[tid] = s;
      } else if (tid >= 64 && tid < 96) {
        const int i = tid - 64;
        float s = y_lds[i];
        #pragma unroll
        for (int k = 0; k < 32; ++k) s = fmaf(-DLDS[i*PA + k], mu_lds[k], s);
        #pragma unroll
        for (int k = 0; k < 16; ++k) s = fmaf(-FL[i*FSTR + k], u_lds[k], s);
        T2T[32*ST + i] = s;
      }
    }
    __syncthreads();

    // ---- P2: SigP = T1@A^T + Q (sym trick) ; T2 = T1P@A^T + CQ (store T2T[col][row]) ;
    //          S = T1P@D^T + E (sym trick) ----
    {
      float p0, p1;
      dot32x2(T1 + r*ST, aq0, aq1, p0, p1);
      float t2a, t2b, sa, sb;
      dot32x4(T1P + r*ST, aq0, aq1, dq0, dq1, t2a, t2b, sa, sb);
      SIGP[ro0] = p0 + QL[q*32 + r];
      SIGP[ro1] = p1 + QL[(q+16)*32 + r];
      T2T[ro0] = t2a + CQT[q*32 + r];        // T2T[q][r] = T2[r][q]
      T2T[ro1] = t2b + CQT[(q+16)*32 + r];
      SR[ro0] = sa + EL[q*32 + r];
      SR[ro1] = sb + EL[(q+16)*32 + r];
    }
    __syncthreads();

    // ---- P3: wave0: Cholesky of S + fwd subst of [T2|r] -> WT;
    //          waves1-7: stream outputs + prefetch next y/u/mask ----
    if (tid < 64) {
      int cc = tid; if (cc > 32) cc = 32;   // lanes 33-63 duplicate lane 32 (harmless)
      float w[32], rr[32];
      #pragma unroll
      for (int kk = 0; kk < 32; kk += 4) {  // row cc ~= column cc (S symmetric)
        float4 vw = ld4(SR + cc*ST + kk);
        w[kk] = vw.x; w[kk+1] = vw.y; w[kk+2] = vw.z; w[kk+3] = vw.w;
        float4 vr = ld4(T2T + cc*ST + kk);  // RHS column cc (cc==32 -> residual)
        rr[kk] = vr.x; rr[kk+1] = vr.y; rr[kk+2] = vr.z; rr[kk+3] = vr.w;
      }
      #pragma unroll
      for (int j = 0; j < 32; ++j) {
        float d  = rdlane(w[j], j);        // pivot (wave-uniform)
        float sj = RSQF(d);                // 1/sqrt(d)
        float s2 = sj * sj;                // 1/d
        float gw = s2 * w[j];
        float gr = s2 * rr[j];
        WT[cc*ST + j] = rr[j] * sj;        // z[j] for column cc
        #pragma unroll
        for (int i = j+1; i < 32; ++i) {
          float bw = rdlane(w[i], j);
          w[i]  = fmaf(-bw, gw, w[i]);
          rr[i] = fmaf(-bw, gr, rr[i]);
        }
      }
    } else {
      const int u = tid - 64;                    // 0..447
      if (u < 256) {
        st4(out + o_Sp + bt*1024 + u*4, ld4(SIGP + (u>>3)*ST + (u&7)*4));
      } else if (t > 0) {
        const int q2 = u - 256;                  // 0..191
        st4(out + o_Sf + (bt-1)*1024 + q2*4, ld4(SIG + (q2>>3)*ST + (q2&7)*4));
      }
      if (u < 64 && t > 0) {
        const int q2 = u + 192;                  // 192..255
        st4(out + o_Sf + (bt-1)*1024 + q2*4, ld4(SIG + (q2>>3)*ST + (q2&7)*4));
      }
      if (tid >= 64 && tid < 96)  out[o_mp + bt*32 + (tid-64)] = mupred[tid-64];
      if (t > 0 && tid >= 96 && tid < 128) out[(bt-1)*32 + (tid-96)] = mu_lds[tid-96];
      if (t < TT-1) {                            // prefetch t+1 (hidden under Cholesky)
        if (tid >= 128 && tid < 144) u_lds[tid-128] = Ug[(bt+1)*16 + (tid-128)];
        if (tid >= 160 && tid < 192) y_lds[tid-160] = Yg[(bt+1)*32 + (tid-160)];
        if (tid == 200) mlds[(t+1)&1] = Mg[bt+1];
      }
    }
    __syncthreads();

    // ---- P4: G[i][j] = dot(WTrow_i, WTrow_j); Sigma' = SigP + (m^2-2m) G ;
    //          mu' = mu_pred + m * dot(WTrow_i, WTrow_32) ----
    {
      const float m = mlds[t&1];
      const float coefS = fmaf(m, m, -2.f*m);   // m^2 - 2m
      float rv[32];
      #pragma unroll
      for (int k = 0; k < 32; k += 4) {
        float4 v = ld4(WT + r*ST + k);
        rv[k] = v.x; rv[k+1] = v.y; rv[k+2] = v.z; rv[k+3] = v.w;
      }
      float ga = dot32r(WT + q*ST, rv);
      float gb = dot32r(WT + (q+16)*ST, rv);
      SIG[ro0] = fmaf(coefS, ga, SIGP[ro0]);
      SIG[ro1] = fmaf(coefS, gb, SIGP[ro1]);
      if (tid < 32) {
        float sacc = dot32rr(WT + tid*ST, WT + 32*ST);
        mu_lds[tid] = fmaf(m, sacc, mupred[tid]);
      }
    }
    __syncthreads();
  }

  // ---- final filtered outputs for t = T-1 ----
  {
    const long bt = btB + TT - 1;
    if (tid < 256)
      st4(out + o_Sf + bt*1024 + tid*4, ld4(SIG + (tid>>3)*ST + (tid&7)*4));
    if (tid >= 480)
      out[bt*32 + (tid - 480)] = mu_lds[tid - 480];
  }
}

extern "C" void kernel_launch(void* const* d_in, const int* in_sizes, int n_in,
                              void* d_out, int out_size, void* d_ws, size_t ws_size,
                              hipStream_t stream) {
  const float* Y   = (const float*)d_in[0];
  const float* U   = (const float*)d_in[1];
  const float* Mk  = (const float*)d_in[2];
  const float* A   = (const float*)d_in[3];
  const float* Bm  = (const float*)d_in[4];
  const float* C   = (const float*)d_in[5];
  const float* mu0 = (const float*)d_in[6];
  const float* S0  = (const float*)d_in[7];
  const float* Q   = (const float*)d_in[8];
  const float* R   = (const float*)d_in[9];
  int Bsz = in_sizes[2] / TT;
  kf_kernel<<<Bsz, 512, 0, stream>>>(Y, U, Mk, A, Bm, C, mu0, S0, Q, R,
                                     (float*)d_out, Bsz);
}